// Round 1
// 820.306 us; speedup vs baseline: 1.2427x; 1.2427x over previous
//
#include <hip/hip_runtime.h>
#include <hip/hip_bf16.h>
#include <stdint.h>

// Problem constants
#define D_MODEL 1024
#define HEADS   16
#define DK      64
#define BATCH   128
#define NTOK    256
#define MROWS   (BATCH * NTOK)   // 32768

typedef __attribute__((ext_vector_type(8))) short bf16x8;
typedef __attribute__((ext_vector_type(4))) float f32x4;

// fp32 -> bf16 round-to-nearest-even
__device__ __forceinline__ unsigned short f2b_rne(float f) {
    union { float f; unsigned int u; } c; c.f = f;
    unsigned int u = c.u;
    unsigned int r = (u + 0x7FFFu + ((u >> 16) & 1u)) >> 16;
    return (unsigned short)r;
}

// async global->LDS, 16B per lane, dest = wave-uniform base + lane*16
__device__ __forceinline__ void async16(const void* g, void* l) {
    __builtin_amdgcn_global_load_lds(
        (__attribute__((address_space(1))) void*)g,
        (__attribute__((address_space(3))) void*)l,
        16, 0, 0);
}

// ---------------- fp32 -> bf16 convert (vectorized) ----------------
__global__ __launch_bounds__(256)
void f2b_kernel(const float* __restrict__ x, ushort* __restrict__ y, int n4) {
    int i = blockIdx.x * blockDim.x + threadIdx.x;
    int stride = gridDim.x * blockDim.x;
    for (; i < n4; i += stride) {
        float4 v = ((const float4*)x)[i];
        ushort4 o;
        o.x = f2b_rne(v.x); o.y = f2b_rne(v.y);
        o.z = f2b_rne(v.z); o.w = f2b_rne(v.w);
        ((ushort4*)y)[i] = o;
    }
}

// ---------------- bf16 NT GEMM, 256x256 tile, BK=64, 8-phase pipeline --------
// C[m,e] = sum_k A[m,k] * B[e,k].  A: M x K bf16 row-major, B: N x K bf16.
// MODE 0: out bf16 permuted scatter dst[(((e>>6)<<8)+(m&255))*128 + (m>>8)]*64+(e&63)
//         value = (acc + bias[e]) * alpha
// MODE 1: out fp32 row-major [m*N + e], value = acc + bias[e]
//
// Structure (T1+T2+T3+T4+T5):
//  - 8 waves (2M x 4N), per-wave output 128x64, acc[8][4] f32x4
//  - LDS 128 KiB = 2 buffers x (A 256x64 | B 256x64) bf16
//  - st-XOR swizzle: phys 16B-slot s of row r holds global slot s^(r&7);
//    written via pre-swizzled per-lane GLOBAL address (linear LDS dest, rule #21)
//  - 4 phases per K-tile: {ds_read subtile; s_barrier; lgkmcnt(0); setprio(1);
//    16 MFMA; setprio(0); s_barrier}
//  - full next-next-tile STAGE (8 global_load_lds/wave) issued right after the
//    tile's last-read barrier; vmcnt(8) ONCE per tile (never 0 in main loop)
template<int MODE>
__global__ __launch_bounds__(512, 2)
void gemm_nt(const ushort* __restrict__ A, const ushort* __restrict__ B,
             const float* __restrict__ bias, void* __restrict__ Cout,
             int M, int N, int K, float alpha)
{
    __shared__ ushort smem[65536];   // 128 KiB: [buf][ A:16384 | B:16384 ]

    const int tid  = threadIdx.x;
    const int wave = tid >> 6, lane = tid & 63;
    const int quad = lane >> 4, l15 = lane & 15;
    const int swz  = l15 & 7;        // row&7 for all fragment rows this lane reads

    // XCD-aware bijective swizzle: 512 blocks = 8 XCDs x 64-chunk, y(pn)-fastest
    // within chunk so the 4 pn-tiles sharing one A-panel run temporally adjacent.
    const int o  = blockIdx.x;
    const int s  = (o & 7) * 64 + (o >> 3);
    const int pm = (s >> 2) * 256;   // 128 m-tiles
    const int pn = (s & 3) * 256;    // 4   n-tiles

    const int arow = (wave >> 2) * 128;   // wave's A-row base within tile
    const int brow = (wave & 3) * 64;     // wave's B-row base within tile

    // staging: lane l covers row (l>>3), phys slot (l&7); global col-slot is
    // pre-swizzled (l&7)^(l>>3) so LDS stays linear (global_load_lds constraint)
    const size_t laneoff = (size_t)(lane >> 3) * K
                         + (size_t)(((lane & 7) ^ (lane >> 3)) << 3);
    const ushort* Ab = A + (size_t)(pm + wave * 32) * K + laneoff;
    const ushort* Bb = B + (size_t)(pn + wave * 32) * K + laneoff;

    f32x4 acc[8][4] = {};
    bf16x8 afrag[4], bfrag[4];

#define STAGE(BUF, kt) do {                                                     \
    const ushort* ag_ = Ab + (size_t)(kt) * 64;                                 \
    const ushort* bg_ = Bb + (size_t)(kt) * 64;                                 \
    _Pragma("unroll")                                                           \
    for (int i_ = 0; i_ < 4; ++i_) {                                            \
        async16(ag_ + (size_t)(i_ * 8) * K,                                     \
                &smem[(BUF) * 32768 + wave * 2048 + i_ * 512]);                 \
        async16(bg_ + (size_t)(i_ * 8) * K,                                     \
                &smem[(BUF) * 32768 + 16384 + wave * 2048 + i_ * 512]);         \
    }                                                                           \
} while (0)

#define LDB(BUF, kkidx) do {                                                    \
    _Pragma("unroll")                                                           \
    for (int n_ = 0; n_ < 4; ++n_)                                              \
        bfrag[n_] = *(const bf16x8*)&smem[(BUF) * 32768 + 16384                 \
            + (brow + n_ * 16 + l15) * 64                                       \
            + ((((kkidx) * 4 + quad) ^ swz) << 3)];                             \
} while (0)

#define LDA(BUF, kkidx, qm) do {                                                \
    _Pragma("unroll")                                                           \
    for (int m_ = 0; m_ < 4; ++m_)                                              \
        afrag[m_] = *(const bf16x8*)&smem[(BUF) * 32768                         \
            + (arow + ((qm) * 4 + m_) * 16 + l15) * 64                          \
            + ((((kkidx) * 4 + quad) ^ swz) << 3)];                             \
} while (0)

#define MFMA16(qm) do {                                                         \
    __builtin_amdgcn_s_setprio(1);                                              \
    _Pragma("unroll")                                                           \
    for (int m_ = 0; m_ < 4; ++m_)                                              \
        _Pragma("unroll")                                                       \
        for (int n_ = 0; n_ < 4; ++n_)                                          \
            acc[(qm) * 4 + m_][n_] = __builtin_amdgcn_mfma_f32_16x16x32_bf16(   \
                afrag[m_], bfrag[n_], acc[(qm) * 4 + m_][n_], 0, 0, 0);         \
    __builtin_amdgcn_s_setprio(0);                                              \
} while (0)

// standard phase: reads issued -> barrier -> lgkm(0) -> MFMA cluster -> barrier
#define PHASE_STD(BUF, kkidx, qm, RB) do {                                      \
    if (RB) LDB(BUF, kkidx);                                                    \
    LDA(BUF, kkidx, qm);                                                        \
    __builtin_amdgcn_s_barrier();                                               \
    asm volatile("s_waitcnt lgkmcnt(0)" ::: "memory");                          \
    __builtin_amdgcn_sched_barrier(0);                                          \
    MFMA16(qm);                                                                 \
    __builtin_amdgcn_s_barrier();                                               \
} while (0)

// last phase of a tile: lgkm BEFORE barrier so post-barrier all waves have
// finished reading BUF -> safe to STAGE tile t+2 into it; counted vmcnt after.
#define PHASE_LAST(BUF, kt, vmN) do {                                           \
    LDA(BUF, 1, 1);                                                             \
    asm volatile("s_waitcnt lgkmcnt(0)" ::: "memory");                          \
    __builtin_amdgcn_sched_barrier(0);                                          \
    __builtin_amdgcn_s_barrier();                                               \
    if ((kt) >= 0) STAGE(BUF, kt);                                              \
    MFMA16(1);                                                                  \
    if ((vmN) == 8)      { asm volatile("s_waitcnt vmcnt(8)" ::: "memory"); }   \
    else if ((vmN) == 0) { asm volatile("s_waitcnt vmcnt(0)" ::: "memory"); }   \
    __builtin_amdgcn_sched_barrier(0);                                          \
    __builtin_amdgcn_s_barrier();                                               \
} while (0)

    // prologue: stage tiles 0 and 1 (8 loads/wave each); wait tile 0 only
    STAGE(0, 0);
    STAGE(1, 1);
    asm volatile("s_waitcnt vmcnt(8)" ::: "memory");
    __builtin_amdgcn_sched_barrier(0);
    __builtin_amdgcn_s_barrier();

    // K = 1024 -> 16 K-tiles of 64, 2 per iteration (buf0 then buf1)
    #pragma unroll 1
    for (int it = 0; it < 8; ++it) {
        const int t2 = 2 * it + 2;
        const int t3 = 2 * it + 3;
        // tile 2it (buf 0): phases (kk0,qm0)(kk0,qm1)(kk1,qm0)(kk1,qm1)
        PHASE_STD(0, 0, 0, 1);
        PHASE_STD(0, 0, 1, 0);
        PHASE_STD(0, 1, 0, 1);
        PHASE_LAST(0, (t2 < 16) ? t2 : -1, (t2 < 16) ? 8 : 0);
        // tile 2it+1 (buf 1)
        PHASE_STD(1, 0, 0, 1);
        PHASE_STD(1, 0, 1, 0);
        PHASE_STD(1, 1, 0, 1);
        PHASE_LAST(1, (t3 < 16) ? t3 : -1, (t3 < 16) ? 8 : -1);
    }

#undef PHASE_LAST
#undef PHASE_STD
#undef MFMA16
#undef LDA
#undef LDB
#undef STAGE

    // epilogue: C/D layout col=l15, row=quad*4+r
    if (MODE == 0) {
        ushort* out = (ushort*)Cout;
        #pragma unroll
        for (int m = 0; m < 8; ++m) {
            const int mbase = pm + arow + m * 16 + quad * 4;
            #pragma unroll
            for (int n = 0; n < 4; ++n) {
                const int e = pn + brow + n * 16 + l15;
                const float bv = bias[e];
                const int h = e >> 6, d = e & 63;
                #pragma unroll
                for (int r = 0; r < 4; ++r) {
                    const int mm = mbase + r;
                    const int bb = mm >> 8, nn = mm & 255;
                    float val = (acc[m][n][r] + bv) * alpha;
                    out[(size_t)(((h << 8) + nn) * 128 + bb) * 64 + d] = f2b_rne(val);
                }
            }
        }
    } else {
        float* out = (float*)Cout;
        #pragma unroll
        for (int m = 0; m < 8; ++m) {
            const int mbase = pm + arow + m * 16 + quad * 4;
            #pragma unroll
            for (int n = 0; n < 4; ++n) {
                const int e = pn + brow + n * 16 + l15;
                const float bv = bias[e];
                #pragma unroll
                for (int r = 0; r < 4; ++r) {
                    const int mm = mbase + r;
                    out[(size_t)mm * N + e] = acc[m][n][r] + bv;
                }
            }
        }
    }
}

// ---------------- intersample attention: one block per (h, n) ----------------
// Qp/Kp/Vp layout: [h][n][b][d] bf16 (scale already folded into Q)
// Output: Ob[(b*256 + n)*1024 + h*64 + d] bf16  (merged-head layout for final GEMM)
__global__ __launch_bounds__(256)
void attn_kernel(const ushort* __restrict__ Qp, const ushort* __restrict__ Kp,
                 const ushort* __restrict__ Vp, ushort* __restrict__ Ob)
{
    __shared__ ushort sm[24576];  // 48KB: sQ[0,8192) sK[8192,16384) sVt[16384,24576); P overlays [0,16384)

    const int tid  = threadIdx.x;
    const int wave = tid >> 6, lane = tid & 63;
    const int quad = lane >> 4, l15 = lane & 15;
    const int hn = blockIdx.x;
    const int h = hn >> 8, n = hn & 255;
    const size_t base = (size_t)hn * (BATCH * DK);

    // load Q, K tiles (contiguous 16KB each) and V transposed (Vt[d][c])
    {
        const uint4* Qg = (const uint4*)(Qp + base);
        const uint4* Kg = (const uint4*)(Kp + base);
        uint4* s4 = (uint4*)sm;
        #pragma unroll
        for (int i = 0; i < 4; i++) {
            int id = tid + i * 256;           // 0..1023 chunks of 8 bf16
            s4[id]        = Qg[id];
            s4[1024 + id] = Kg[id];
        }
        const uint4* Vg = (const uint4*)(Vp + base);
        #pragma unroll
        for (int i = 0; i < 4; i++) {
            int id = tid + i * 256;
            int c = id >> 3, d8 = (id & 7) * 8;
            uint4 vv = Vg[id];
            const ushort* vs = (const ushort*)&vv;
            #pragma unroll
            for (int j = 0; j < 8; j++)
                sm[16384 + (d8 + j) * 128 + c] = vs[j];
        }
    }
    __syncthreads();

    // S = Q K^T : wave handles rows [wave*32, wave*32+32), all 128 cols
    f32x4 accs[2][8] = {};
    #pragma unroll
    for (int kk = 0; kk < 64; kk += 32) {
        bf16x8 aq[2], bk8[8];
        #pragma unroll
        for (int mt = 0; mt < 2; mt++)
            aq[mt] = *(const bf16x8*)&sm[(wave * 32 + mt * 16 + l15) * 64 + kk + quad * 8];
        #pragma unroll
        for (int nt = 0; nt < 8; nt++)
            bk8[nt] = *(const bf16x8*)&sm[8192 + (nt * 16 + l15) * 64 + kk + quad * 8];
        #pragma unroll
        for (int mt = 0; mt < 2; mt++)
            #pragma unroll
            for (int nt = 0; nt < 8; nt++)
                accs[mt][nt] = __builtin_amdgcn_mfma_f32_16x16x32_bf16(aq[mt], bk8[nt], accs[mt][nt], 0, 0, 0);
    }

    // rowwise softmax in registers: row r held by the 16 lanes of this quad group
    #pragma unroll
    for (int mt = 0; mt < 2; mt++) {
        #pragma unroll
        for (int r = 0; r < 4; r++) {
            float mx = accs[mt][0][r];
            #pragma unroll
            for (int nt = 1; nt < 8; nt++) mx = fmaxf(mx, accs[mt][nt][r]);
            #pragma unroll
            for (int s = 1; s < 16; s <<= 1) mx = fmaxf(mx, __shfl_xor(mx, s, 64));
            float sum = 0.f;
            #pragma unroll
            for (int nt = 0; nt < 8; nt++) {
                float e = __expf(accs[mt][nt][r] - mx);
                accs[mt][nt][r] = e;
                sum += e;
            }
            #pragma unroll
            for (int s = 1; s < 16; s <<= 1) sum += __shfl_xor(sum, s, 64);
            float inv = 1.0f / sum;
            #pragma unroll
            for (int nt = 0; nt < 8; nt++) accs[mt][nt][r] *= inv;
        }
    }

    __syncthreads();  // all waves done reading sQ/sK before P overwrite

    // write P (bf16, C-layout -> row-major) into sm[0,16384)
    #pragma unroll
    for (int mt = 0; mt < 2; mt++)
        #pragma unroll
        for (int nt = 0; nt < 8; nt++)
            #pragma unroll
            for (int r = 0; r < 4; r++)
                sm[(wave * 32 + mt * 16 + quad * 4 + r) * 128 + nt * 16 + l15] =
                    f2b_rne(accs[mt][nt][r]);
    __syncthreads();

    // O = P V : P[b][c] at sm[0], Vt[d][c] at sm[16384]
    f32x4 acco[2][4] = {};
    #pragma unroll
    for (int kk = 0; kk < 128; kk += 32) {
        bf16x8 ap[2], bv8[4];
        #pragma unroll
        for (int mt = 0; mt < 2; mt++)
            ap[mt] = *(const bf16x8*)&sm[(wave * 32 + mt * 16 + l15) * 128 + kk + quad * 8];
        #pragma unroll
        for (int nt = 0; nt < 4; nt++)
            bv8[nt] = *(const bf16x8*)&sm[16384 + (nt * 16 + l15) * 128 + kk + quad * 8];
        #pragma unroll
        for (int mt = 0; mt < 2; mt++)
            #pragma unroll
            for (int nt = 0; nt < 4; nt++)
                acco[mt][nt] = __builtin_amdgcn_mfma_f32_16x16x32_bf16(ap[mt], bv8[nt], acco[mt][nt], 0, 0, 0);
    }

    #pragma unroll
    for (int mt = 0; mt < 2; mt++)
        #pragma unroll
        for (int nt = 0; nt < 4; nt++)
            #pragma unroll
            for (int r = 0; r < 4; r++) {
                int b = wave * 32 + mt * 16 + quad * 4 + r;
                int d = nt * 16 + l15;
                Ob[((size_t)b * NTOK + n) * D_MODEL + h * DK + d] = f2b_rne(acco[mt][nt][r]);
            }
}

extern "C" void kernel_launch(void* const* d_in, const int* in_sizes, int n_in,
                              void* d_out, int out_size, void* d_ws, size_t ws_size,
                              hipStream_t stream)
{
    const float* q  = (const float*)d_in[0];
    const float* k  = (const float*)d_in[1];
    const float* v  = (const float*)d_in[2];
    const float* Wq = (const float*)d_in[3];
    const float* bq = (const float*)d_in[4];
    const float* Wk = (const float*)d_in[5];
    const float* bk = (const float*)d_in[6];
    const float* Wv = (const float*)d_in[7];
    const float* bv = (const float*)d_in[8];
    const float* Wo = (const float*)d_in[9];
    const float* bo = (const float*)d_in[10];

    const int XE = MROWS * D_MODEL;       // 33,554,432 activation elements
    const int WE = D_MODEL * D_MODEL;     // 1,048,576 weight elements

    // workspace (bf16 as ushort): xb | Kp | Vp | Wb(x4)  = 200 MiB
    ushort* xb = (ushort*)d_ws;
    ushort* Kp = xb + (size_t)XE;
    ushort* Vp = Kp + (size_t)XE;
    ushort* Wb = Vp + (size_t)XE;
    // Qp (64 MiB) lives in d_out (128 MiB fp32) — consumed before the final GEMM writes it
    ushort* Qp = (ushort*)d_out;

    dim3 blk(256);
    dim3 gblk(512);
    dim3 ggemm(512);   // (M/256) x (N/256) = 128 x 4 tiles, XCD-swizzled in-kernel

    // convert weights to bf16 (once per call)
    f2b_kernel<<<dim3(512),  blk, 0, stream>>>(Wq, Wb + 0 * (size_t)WE, WE / 4);
    f2b_kernel<<<dim3(512),  blk, 0, stream>>>(Wk, Wb + 1 * (size_t)WE, WE / 4);
    f2b_kernel<<<dim3(512),  blk, 0, stream>>>(Wv, Wb + 2 * (size_t)WE, WE / 4);
    f2b_kernel<<<dim3(512),  blk, 0, stream>>>(Wo, Wb + 3 * (size_t)WE, WE / 4);

    // Q projection (scale 1/8 folded in), permuted to [h][n][b][d]
    f2b_kernel<<<dim3(4096), blk, 0, stream>>>(q, xb, XE / 4);
    gemm_nt<0><<<ggemm, gblk, 0, stream>>>(xb, Wb + 0 * (size_t)WE, bq, Qp,
                                           MROWS, D_MODEL, D_MODEL, 0.125f);
    // K projection
    f2b_kernel<<<dim3(4096), blk, 0, stream>>>(k, xb, XE / 4);
    gemm_nt<0><<<ggemm, gblk, 0, stream>>>(xb, Wb + 1 * (size_t)WE, bk, Kp,
                                           MROWS, D_MODEL, D_MODEL, 1.0f);
    // V projection
    f2b_kernel<<<dim3(4096), blk, 0, stream>>>(v, xb, XE / 4);
    gemm_nt<0><<<ggemm, gblk, 0, stream>>>(xb, Wb + 2 * (size_t)WE, bv, Vp,
                                           MROWS, D_MODEL, D_MODEL, 1.0f);

    // intersample attention: one block per (h, n); writes merged-head bf16 into xb
    attn_kernel<<<dim3(HEADS * NTOK), blk, 0, stream>>>(Qp, Kp, Vp, xb);

    // output projection -> fp32 d_out
    gemm_nt<1><<<ggemm, gblk, 0, stream>>>(xb, Wb + 3 * (size_t)WE, bo, d_out,
                                           MROWS, D_MODEL, D_MODEL, 1.0f);
}